// Round 1
// baseline (269.802 us; speedup 1.0000x reference)
//
#include <hip/hip_runtime.h>
#include <hip/hip_bf16.h>
#include <stdint.h>

// Problem constants
#define BATCH 2048
#define FDIM 512
#define CDIM 64

typedef unsigned short ushort_t;
typedef __attribute__((ext_vector_type(8))) short short8;
typedef __attribute__((ext_vector_type(4))) float f32x4;

__device__ __forceinline__ ushort_t f2bf(float x) {
    union { float f; uint32_t u; } v; v.f = x;
    uint32_t u = v.u;
    uint32_t r = u + 0x7FFFu + ((u >> 16) & 1u);  // round-to-nearest-even
    return (ushort_t)(r >> 16);
}

// ---- kernel 1: t_feat fp32 -> bf16 (row layout unchanged: [b][i]) ----
__global__ void convert_t_kernel(const float* __restrict__ t, ushort_t* __restrict__ t16) {
    int idx = blockIdx.x * 256 + threadIdx.x;   // each handles 4 elems
    const float4* t4 = (const float4*)t;
    float4 v = t4[idx];
    ushort_t p[4] = { f2bf(v.x), f2bf(v.y), f2bf(v.z), f2bf(v.w) };
    *(uint2*)&t16[idx * 4] = *(uint2*)p;        // 8B store
}

// ---- kernel 2: W_proj fp32 [c][i*512+j] -> bf16 transposed Wt[c][j][i] ----
__global__ void transpose_w_kernel(const float* __restrict__ W, ushort_t* __restrict__ Wt) {
    __shared__ float tile[32][33];
    int c = blockIdx.z;
    int i0 = blockIdx.x * 32;
    int j0 = blockIdx.y * 32;
    int tx = threadIdx.x;   // 0..31
    int ty = threadIdx.y;   // 0..7
    const float* Wc = W + (size_t)c * (FDIM * FDIM);
    #pragma unroll
    for (int q = 0; q < 4; q++) {
        int p = ty + q * 8;
        tile[p][tx] = Wc[(size_t)(i0 + p) * FDIM + j0 + tx];
    }
    __syncthreads();
    ushort_t* Wtc = Wt + (size_t)c * (FDIM * FDIM);
    #pragma unroll
    for (int q = 0; q < 4; q++) {
        int p = ty + q * 8;
        Wtc[(size_t)(j0 + p) * FDIM + i0 + tx] = f2bf(tile[tx][p]);
    }
}

// ---- kernel 3: fused GEMM + f-contraction ----
// Block tile: 128 b  x 128 j, one c, K=512 over i (BK=32).
// tmp2[b][j] = sum_i t16[b][i] * Wt[c][j][i]; proj[b][c] += sum_j tmp2[b][j]*f[b][j]
#define AS3(p) ((__attribute__((address_space(3))) void*)(p))
#define AS1(p) ((const __attribute__((address_space(1))) void*)(p))

__launch_bounds__(256, 2)
__global__ void gemm_fused_kernel(const ushort_t* __restrict__ t16,
                                  const ushort_t* __restrict__ Wt,
                                  const float* __restrict__ f_feat,
                                  float* __restrict__ proj) {
    __shared__ ushort_t As[128 * 32];   // [m][k] 64B rows
    __shared__ ushort_t Bs[128 * 32];   // [n][k] 64B rows (B^T layout)

    const int tid  = threadIdx.x;
    const int wave = tid >> 6;
    const int lane = tid & 63;
    const int l15  = lane & 15;
    const int lg   = lane >> 4;

    const int b0 = blockIdx.x * 128;
    const int c  = blockIdx.y;
    const int j0 = blockIdx.z * 128;

    const ushort_t* Wc = Wt + (size_t)c * (FDIM * FDIM);

    const int m_base = (wave >> 1) * 64;
    const int n_base = (wave & 1) * 64;

    f32x4 acc[4][4];
    #pragma unroll
    for (int mi = 0; mi < 4; mi++)
        #pragma unroll
        for (int ni = 0; ni < 4; ni++)
            acc[mi][ni] = (f32x4){0.f, 0.f, 0.f, 0.f};

    const int row  = tid >> 2;          // 0..63
    const int cof  = (tid & 3) * 8;     // k-subchunk (elems)

    for (int k0 = 0; k0 < FDIM; k0 += 32) {
        // stage A (t16): 128 rows x 32 k  (two 64-row halves)
        {
            const ushort_t* g0 = t16 + (size_t)(b0 + row) * FDIM + k0 + cof;
            const ushort_t* g1 = t16 + (size_t)(b0 + 64 + row) * FDIM + k0 + cof;
            __builtin_amdgcn_global_load_lds(AS1(g0), AS3(&As[0 * 2048 + wave * 512]), 16, 0, 0);
            __builtin_amdgcn_global_load_lds(AS1(g1), AS3(&As[1 * 2048 + wave * 512]), 16, 0, 0);
        }
        // stage B (Wt): 128 rows (j) x 32 k (i)
        {
            const ushort_t* g0 = Wc + (size_t)(j0 + row) * FDIM + k0 + cof;
            const ushort_t* g1 = Wc + (size_t)(j0 + 64 + row) * FDIM + k0 + cof;
            __builtin_amdgcn_global_load_lds(AS1(g0), AS3(&Bs[0 * 2048 + wave * 512]), 16, 0, 0);
            __builtin_amdgcn_global_load_lds(AS1(g1), AS3(&Bs[1 * 2048 + wave * 512]), 16, 0, 0);
        }
        __syncthreads();

        short8 a[4], b[4];
        #pragma unroll
        for (int mi = 0; mi < 4; mi++)
            a[mi] = *(const short8*)&As[(m_base + mi * 16 + l15) * 32 + lg * 8];
        #pragma unroll
        for (int ni = 0; ni < 4; ni++)
            b[ni] = *(const short8*)&Bs[(n_base + ni * 16 + l15) * 32 + lg * 8];

        #pragma unroll
        for (int mi = 0; mi < 4; mi++)
            #pragma unroll
            for (int ni = 0; ni < 4; ni++)
                acc[mi][ni] = __builtin_amdgcn_mfma_f32_16x16x32_bf16(a[mi], b[ni], acc[mi][ni], 0, 0, 0);

        __syncthreads();
    }

    // Epilogue: contract with f over this block's 128-j range, reduce, atomicAdd.
    // D mapping: col = lane&15, row = (lane>>4)*4 + reg
    #pragma unroll
    for (int mi = 0; mi < 4; mi++) {
        #pragma unroll
        for (int r = 0; r < 4; r++) {
            int b_idx = b0 + m_base + mi * 16 + lg * 4 + r;
            float s = 0.f;
            #pragma unroll
            for (int ni = 0; ni < 4; ni++) {
                int j = j0 + n_base + ni * 16 + l15;
                s += acc[mi][ni][r] * f_feat[(size_t)b_idx * FDIM + j];
            }
            // reduce across the 16 lanes (l15) that share this b
            s += __shfl_xor(s, 1, 64);
            s += __shfl_xor(s, 2, 64);
            s += __shfl_xor(s, 4, 64);
            s += __shfl_xor(s, 8, 64);
            if (l15 == 0)
                atomicAdd(&proj[(size_t)b_idx * CDIM + c], s);
        }
    }
}

// ---- kernel 4: MLP head ----
__global__ void mlp_kernel(const float* __restrict__ proj,
                           const float* __restrict__ b_proj,
                           const float* __restrict__ W1, const float* __restrict__ b1,
                           const float* __restrict__ W2, const float* __restrict__ b2,
                           float* __restrict__ out) {
    int b = blockIdx.x * 256 + threadIdx.x;
    float h[64];
    #pragma unroll
    for (int c = 0; c < 64; c++) {
        float v = proj[(size_t)b * CDIM + c] + b_proj[c];
        h[c] = v > 0.f ? v : 0.f;
    }
    float logit = b2[0];
    for (int o = 0; o < 32; o++) {
        float s = b1[o];
        #pragma unroll
        for (int c = 0; c < 64; c++) s += h[c] * W1[o * 64 + c];
        s = s > 0.f ? s : 0.f;
        logit += s * W2[o];
    }
    out[b] = logit;
}

extern "C" void kernel_launch(void* const* d_in, const int* in_sizes, int n_in,
                              void* d_out, int out_size, void* d_ws, size_t ws_size,
                              hipStream_t stream) {
    const float* t_feat = (const float*)d_in[0];
    const float* f_feat = (const float*)d_in[1];
    const float* W_proj = (const float*)d_in[2];
    const float* b_proj = (const float*)d_in[3];
    const float* W1     = (const float*)d_in[4];
    const float* b1     = (const float*)d_in[5];
    const float* W2     = (const float*)d_in[6];
    const float* b2     = (const float*)d_in[7];
    float* out = (float*)d_out;

    // workspace layout
    uint8_t* ws = (uint8_t*)d_ws;
    ushort_t* Wt   = (ushort_t*)(ws);                       // 64*512*512*2 = 32 MiB
    ushort_t* t16  = (ushort_t*)(ws + 33554432);            // 2048*512*2   = 2 MiB
    float*    proj = (float*)(ws + 33554432 + 2097152);     // 2048*64*4    = 512 KiB

    // 1) conversions
    convert_t_kernel<<<dim3(BATCH * FDIM / 1024), dim3(256), 0, stream>>>(t_feat, t16);
    transpose_w_kernel<<<dim3(16, 16, 64), dim3(32, 8), 0, stream>>>(W_proj, Wt);

    // 2) zero proj accumulator
    hipMemsetAsync(proj, 0, (size_t)BATCH * CDIM * sizeof(float), stream);

    // 3) fused GEMM + f contraction
    gemm_fused_kernel<<<dim3(BATCH / 128, CDIM, FDIM / 128), dim3(256), 0, stream>>>(
        t16, Wt, f_feat, proj);

    // 4) MLP head
    mlp_kernel<<<dim3(BATCH / 256), dim3(256), 0, stream>>>(proj, b_proj, W1, b1, W2, b2, out);
}

// Round 2
// 231.493 us; speedup vs baseline: 1.1655x; 1.1655x over previous
//
#include <hip/hip_runtime.h>
#include <hip/hip_bf16.h>
#include <stdint.h>

#define BATCH 2048
#define FDIM 512
#define CDIM 64

typedef unsigned short ushort_t;
typedef __attribute__((ext_vector_type(8))) short short8;
typedef __attribute__((ext_vector_type(4))) float f32x4;

__device__ __forceinline__ ushort_t f2bf(float x) {
    union { float f; uint32_t u; } v; v.f = x;
    uint32_t u = v.u;
    uint32_t r = u + 0x7FFFu + ((u >> 16) & 1u);  // round-to-nearest-even
    return (ushort_t)(r >> 16);
}

// ---- fp32 -> bf16 straight cast (used for W_proj and f_feat) ----
__global__ void convert_kernel(const float* __restrict__ src, ushort_t* __restrict__ dst) {
    int idx = blockIdx.x * 256 + threadIdx.x;   // 4 elems per thread
    float4 v = ((const float4*)src)[idx];
    ushort_t p[4] = { f2bf(v.x), f2bf(v.y), f2bf(v.z), f2bf(v.w) };
    *(uint2*)&dst[idx * 4] = *(uint2*)p;
}

// ---- fused GEMM (flipped): u[b, n] = sum_j f16[b,j] * Wb[n,j],  n = c*512 + i
//      epilogue: part[b,c,iq] = sum_{i in tile} u[b,n] * t_feat[b,i]
#define AS3(p) ((__attribute__((address_space(3))) void*)(p))
#define AS1(p) ((const __attribute__((address_space(1))) void*)(p))

__launch_bounds__(256, 2)
__global__ void gemm_fused_kernel(const ushort_t* __restrict__ f16,
                                  const ushort_t* __restrict__ Wb,
                                  const float* __restrict__ t_feat,
                                  float* __restrict__ part) {
    __shared__ ushort_t As[128 * 32];   // f16 tile  [row=b][k=j], 64B rows, k-chunk swizzled
    __shared__ ushort_t Bs[128 * 32];   // Wb tile   [row perm(n)][k=j], swizzled
    __shared__ float scratch[256];

    const int tid  = threadIdx.x;
    const int wave = tid >> 6;
    const int lane = tid & 63;
    const int l15  = lane & 15;
    const int lg   = lane >> 4;

    const int b0 = blockIdx.x * 128;
    const int n0 = blockIdx.y * 128;    // n = c*512 + i

    const int m_base = (wave >> 1) * 64;
    const int nh     = wave & 1;        // which n-half of the tile
    const int n_base = nh * 64;

    f32x4 acc[4][4];
    #pragma unroll
    for (int mi = 0; mi < 4; mi++)
        #pragma unroll
        for (int ni = 0; ni < 4; ni++)
            acc[mi][ni] = (f32x4){0.f, 0.f, 0.f, 0.f};

    // staging geometry: lane tid writes phys (row p, chunk cph) of its half-tile;
    // k-swizzle: that slot holds global chunk cg = cph ^ ((p>>1)&3)
    // B row-permute: phys row p holds global n_local = ((p&15)<<2) | (p>>4)
    const int p    = tid >> 2;                        // 0..63
    const int cph  = tid & 3;
    const int cg   = cph ^ ((p >> 1) & 3);
    const int nrot = ((p & 15) << 2) | (p >> 4);

    const ushort_t* gA0 = f16 + (size_t)(b0 + p) * FDIM + cg * 8;
    const ushort_t* gA1 = f16 + (size_t)(b0 + 64 + p) * FDIM + cg * 8;
    const ushort_t* gB0 = Wb + (size_t)(n0 + nrot) * FDIM + cg * 8;
    const ushort_t* gB1 = Wb + (size_t)(n0 + 64 + nrot) * FDIM + cg * 8;

    for (int k0 = 0; k0 < FDIM; k0 += 32) {
        __builtin_amdgcn_global_load_lds(AS1(gA0 + k0), AS3(&As[0 * 2048 + wave * 512]), 16, 0, 0);
        __builtin_amdgcn_global_load_lds(AS1(gA1 + k0), AS3(&As[1 * 2048 + wave * 512]), 16, 0, 0);
        __builtin_amdgcn_global_load_lds(AS1(gB0 + k0), AS3(&Bs[0 * 2048 + wave * 512]), 16, 0, 0);
        __builtin_amdgcn_global_load_lds(AS1(gB1 + k0), AS3(&Bs[1 * 2048 + wave * 512]), 16, 0, 0);
        __syncthreads();

        short8 a[4], b[4];
        #pragma unroll
        for (int mi = 0; mi < 4; mi++) {
            int r = m_base + mi * 16 + l15;
            a[mi] = *(const short8*)&As[r * 32 + (lg ^ ((r >> 1) & 3)) * 8];
        }
        #pragma unroll
        for (int ni = 0; ni < 4; ni++) {
            int q = n_base + ni * 16 + l15;
            b[ni] = *(const short8*)&Bs[q * 32 + (lg ^ ((q >> 1) & 3)) * 8];
        }

        #pragma unroll
        for (int mi = 0; mi < 4; mi++)
            #pragma unroll
            for (int ni = 0; ni < 4; ni++)
                acc[mi][ni] = __builtin_amdgcn_mfma_f32_16x16x32_bf16(a[mi], b[ni], acc[mi][ni], 0, 0, 0);

        __syncthreads();
    }

    // Epilogue. With the B row-permute, D col l15 of frag ni holds global
    //   n = n0 + n_base + l15*4 + ni  ->  4 consecutive i per lane.
    // D row = lg*4 + reg  -> b.
    const int c  = n0 >> 9;
    const int iq = (n0 >> 7) & 3;
    const int i_base = (n0 & 511) + n_base + l15 * 4;

    #pragma unroll
    for (int mi = 0; mi < 4; mi++) {
        #pragma unroll
        for (int r = 0; r < 4; r++) {
            int b_idx = b0 + m_base + mi * 16 + lg * 4 + r;
            const float4 tv = *(const float4*)&t_feat[(size_t)b_idx * FDIM + i_base];
            float s = acc[mi][0][r] * tv.x + acc[mi][1][r] * tv.y
                    + acc[mi][2][r] * tv.z + acc[mi][3][r] * tv.w;
            s += __shfl_xor(s, 1, 64);
            s += __shfl_xor(s, 2, 64);
            s += __shfl_xor(s, 4, 64);
            s += __shfl_xor(s, 8, 64);
            if (l15 == 0)
                scratch[(m_base + mi * 16 + lg * 4 + r) * 2 + nh] = s;
        }
    }
    __syncthreads();
    if (tid < 128) {
        float v = scratch[tid * 2] + scratch[tid * 2 + 1];
        part[(((size_t)(b0 + tid)) * 64 + c) * 4 + iq] = v;
    }
}

// ---- MLP head: sum 4 partials, bias+relu, 64->32->1 ----
__global__ void mlp_kernel(const float* __restrict__ part,
                           const float* __restrict__ b_proj,
                           const float* __restrict__ W1, const float* __restrict__ b1,
                           const float* __restrict__ W2, const float* __restrict__ b2,
                           float* __restrict__ out) {
    int b = blockIdx.x * 64 + threadIdx.x;
    float h[64];
    const float4* p4 = (const float4*)&part[(size_t)b * 256];
    #pragma unroll
    for (int c = 0; c < 64; c++) {
        float4 v = p4[c];
        float s = v.x + v.y + v.z + v.w + b_proj[c];
        h[c] = s > 0.f ? s : 0.f;
    }
    float logit = b2[0];
    for (int o = 0; o < 32; o++) {
        float s = b1[o];
        #pragma unroll
        for (int c = 0; c < 64; c++) s += h[c] * W1[o * 64 + c];
        logit += (s > 0.f ? s : 0.f) * W2[o];
    }
    out[b] = logit;
}

extern "C" void kernel_launch(void* const* d_in, const int* in_sizes, int n_in,
                              void* d_out, int out_size, void* d_ws, size_t ws_size,
                              hipStream_t stream) {
    const float* t_feat = (const float*)d_in[0];
    const float* f_feat = (const float*)d_in[1];
    const float* W_proj = (const float*)d_in[2];
    const float* b_proj = (const float*)d_in[3];
    const float* W1     = (const float*)d_in[4];
    const float* b1     = (const float*)d_in[5];
    const float* W2     = (const float*)d_in[6];
    const float* b2     = (const float*)d_in[7];
    float* out = (float*)d_out;

    // workspace layout
    uint8_t* ws = (uint8_t*)d_ws;
    ushort_t* Wb   = (ushort_t*)(ws);                     // 64*512*512*2 = 32 MiB
    ushort_t* f16  = (ushort_t*)(ws + 33554432);          // 2048*512*2   = 2 MiB
    float*    part = (float*)(ws + 33554432 + 2097152);   // 2048*64*4*4  = 2 MiB

    // 1) conversions (straight casts; W needs no transpose in flipped GEMM)
    convert_kernel<<<dim3((CDIM * FDIM * FDIM) / 1024), dim3(256), 0, stream>>>(W_proj, Wb);
    convert_kernel<<<dim3((BATCH * FDIM) / 1024), dim3(256), 0, stream>>>(f_feat, f16);

    // 2) fused GEMM + t contraction -> partials (no atomics, no memset)
    gemm_fused_kernel<<<dim3(BATCH / 128, (CDIM * FDIM) / 128), dim3(256), 0, stream>>>(
        f16, Wb, t_feat, part);

    // 3) MLP head
    mlp_kernel<<<dim3(BATCH / 64), dim3(64), 0, stream>>>(part, b_proj, W1, b1, W2, b2, out);
}

// Round 3
// 217.075 us; speedup vs baseline: 1.2429x; 1.0664x over previous
//
#include <hip/hip_runtime.h>
#include <hip/hip_bf16.h>
#include <stdint.h>

#define BATCH 2048
#define FDIM 512
#define CDIM 64

typedef unsigned short ushort_t;
typedef __attribute__((ext_vector_type(8))) short short8;
typedef __attribute__((ext_vector_type(4))) float f32x4;

__device__ __forceinline__ ushort_t f2bf(float x) {
    union { float f; uint32_t u; } v; v.f = x;
    uint32_t u = v.u;
    uint32_t r = u + 0x7FFFu + ((u >> 16) & 1u);  // round-to-nearest-even
    return (ushort_t)(r >> 16);
}

// ---- fp32 -> bf16 cast, 8 elems / thread, 16B stores ----
__global__ void convert_kernel(const float* __restrict__ src, ushort_t* __restrict__ dst) {
    int idx = blockIdx.x * 256 + threadIdx.x;
    float4 v0 = ((const float4*)src)[idx * 2];
    float4 v1 = ((const float4*)src)[idx * 2 + 1];
    ushort_t p[8] = { f2bf(v0.x), f2bf(v0.y), f2bf(v0.z), f2bf(v0.w),
                      f2bf(v1.x), f2bf(v1.y), f2bf(v1.z), f2bf(v1.w) };
    *(uint4*)&dst[idx * 8] = *(uint4*)p;
}

// ---- fused GEMM (flipped): u[b, n] = sum_j f16[b,j] * Wb[n,j],  n = c*512 + i
//      epilogue: part[b,c,iq] = sum_{i in tile} u[b,n] * t_feat[b,i]
// BK=64, XCD-swizzled block mapping.
#define AS3(p) ((__attribute__((address_space(3))) void*)(p))
#define AS1(p) ((const __attribute__((address_space(1))) void*)(p))

__launch_bounds__(256, 2)
__global__ void gemm_fused_kernel(const ushort_t* __restrict__ f16,
                                  const ushort_t* __restrict__ Wb,
                                  const float* __restrict__ t_feat,
                                  float* __restrict__ part) {
    __shared__ ushort_t As[128 * 64];   // [prow][pchunk] 128B rows, chunk-swizzled
    __shared__ ushort_t Bs[128 * 64];   // row-permuted (within 64-halves) + chunk-swizzled
    __shared__ float scratch[256];

    const int tid  = threadIdx.x;
    const int wave = tid >> 6;
    const int lane = tid & 63;
    const int l15  = lane & 15;
    const int lg   = lane >> 4;

    // XCD-aware swizzle: xcd = linear%8 (heuristic). Each XCD owns 32 n-tiles,
    // b-tiles iterate innermost -> W tile stays in that XCD's L2 for 16 blocks.
    const int g   = blockIdx.x + (blockIdx.y << 4);
    const int xcd = g & 7;
    const int s   = g >> 3;
    const int b0  = (s & 15) << 7;
    const int n0  = (xcd * 32 + (s >> 4)) << 7;    // n = c*512 + i

    const int m_base = (wave >> 1) * 64;
    const int nh     = wave & 1;
    const int n_base = nh * 64;

    f32x4 acc[4][4];
    #pragma unroll
    for (int mi = 0; mi < 4; mi++)
        #pragma unroll
        for (int ni = 0; ni < 4; ni++)
            acc[mi][ni] = (f32x4){0.f, 0.f, 0.f, 0.f};

    // Staging: 4 segments/wave each for A and B. Segment seg covers phys rows
    // seg*8..seg*8+7; lane -> prow = seg*8 + (lane>>3), pchunk = lane&7.
    // Content swizzle: phys (prow, pchunk) holds global chunk pchunk^(prow&7).
    // B row-permute within each 64-half: phys row p holds global
    //   (p&64) | ((p&15)<<2) | ((p>>4)&3).
    const ushort_t* srcA[4];
    const ushort_t* srcB[4];
    #pragma unroll
    for (int q = 0; q < 4; q++) {
        int seg  = wave * 4 + q;
        int prow = seg * 8 + (lane >> 3);
        int pch  = lane & 7;
        int gch  = pch ^ (prow & 7);
        srcA[q] = f16 + (size_t)(b0 + prow) * FDIM + gch * 8;
        int grow = (prow & 64) | ((prow & 15) << 2) | ((prow >> 4) & 3);
        srcB[q] = Wb + (size_t)(n0 + grow) * FDIM + gch * 8;
    }

    for (int k0 = 0; k0 < FDIM; k0 += 64) {
        #pragma unroll
        for (int q = 0; q < 4; q++) {
            int seg = wave * 4 + q;
            __builtin_amdgcn_global_load_lds(AS1(srcA[q] + k0), AS3(&As[seg * 512]), 16, 0, 0);
            __builtin_amdgcn_global_load_lds(AS1(srcB[q] + k0), AS3(&Bs[seg * 512]), 16, 0, 0);
        }
        __syncthreads();

        #pragma unroll
        for (int w = 0; w < 2; w++) {
            short8 a[4], b[4];
            #pragma unroll
            for (int mi = 0; mi < 4; mi++) {
                int r  = m_base + mi * 16 + l15;
                int pc = (w * 4 + lg) ^ (r & 7);
                a[mi] = *(const short8*)&As[r * 64 + pc * 8];
            }
            #pragma unroll
            for (int ni = 0; ni < 4; ni++) {
                int q2 = n_base + ni * 16 + l15;
                int pc = (w * 4 + lg) ^ (q2 & 7);
                b[ni] = *(const short8*)&Bs[q2 * 64 + pc * 8];
            }
            #pragma unroll
            for (int mi = 0; mi < 4; mi++)
                #pragma unroll
                for (int ni = 0; ni < 4; ni++)
                    acc[mi][ni] = __builtin_amdgcn_mfma_f32_16x16x32_bf16(a[mi], b[ni], acc[mi][ni], 0, 0, 0);
        }
        __syncthreads();
    }

    // Epilogue. D col l15 of frag ni holds global n = n0 + n_base + l15*4 + ni
    // (4 consecutive i per lane). D row = lg*4 + reg -> b.
    const int c  = n0 >> 9;
    const int iq = (n0 >> 7) & 3;
    const int i_base = (n0 & 511) + n_base + l15 * 4;

    #pragma unroll
    for (int mi = 0; mi < 4; mi++) {
        #pragma unroll
        for (int r = 0; r < 4; r++) {
            int b_idx = b0 + m_base + mi * 16 + lg * 4 + r;
            const float4 tv = *(const float4*)&t_feat[(size_t)b_idx * FDIM + i_base];
            float sv = acc[mi][0][r] * tv.x + acc[mi][1][r] * tv.y
                     + acc[mi][2][r] * tv.z + acc[mi][3][r] * tv.w;
            sv += __shfl_xor(sv, 1, 64);
            sv += __shfl_xor(sv, 2, 64);
            sv += __shfl_xor(sv, 4, 64);
            sv += __shfl_xor(sv, 8, 64);
            if (l15 == 0)
                scratch[(m_base + mi * 16 + lg * 4 + r) * 2 + nh] = sv;
        }
    }
    __syncthreads();
    if (tid < 128) {
        float v = scratch[tid * 2] + scratch[tid * 2 + 1];
        part[(((size_t)(b0 + tid)) * 64 + c) * 4 + iq] = v;
    }
}

// ---- MLP head: 32 threads per batch row, shuffle-reduced ----
__global__ void mlp_kernel(const float* __restrict__ part,
                           const float* __restrict__ b_proj,
                           const float* __restrict__ W1, const float* __restrict__ b1,
                           const float* __restrict__ W2, const float* __restrict__ b2,
                           float* __restrict__ out) {
    __shared__ float h[8][64];
    const int tid = threadIdx.x;
    const int bl  = tid >> 5;        // 0..7
    const int o   = tid & 31;
    const int b   = blockIdx.x * 8 + bl;

    #pragma unroll
    for (int c = o; c < 64; c += 32) {
        float4 v = *(const float4*)&part[(((size_t)b * 64 + c)) * 4];
        float sv = v.x + v.y + v.z + v.w + b_proj[c];
        h[bl][c] = sv > 0.f ? sv : 0.f;
    }
    __syncthreads();

    float sv = b1[o];
    #pragma unroll
    for (int c = 0; c < 64; c++) sv += h[bl][c] * W1[o * 64 + c];
    float v = (sv > 0.f ? sv : 0.f) * W2[o];
    v += __shfl_xor(v, 1, 32);
    v += __shfl_xor(v, 2, 32);
    v += __shfl_xor(v, 4, 32);
    v += __shfl_xor(v, 8, 32);
    v += __shfl_xor(v, 16, 32);
    if (o == 0) out[b] = v + b2[0];
}

extern "C" void kernel_launch(void* const* d_in, const int* in_sizes, int n_in,
                              void* d_out, int out_size, void* d_ws, size_t ws_size,
                              hipStream_t stream) {
    const float* t_feat = (const float*)d_in[0];
    const float* f_feat = (const float*)d_in[1];
    const float* W_proj = (const float*)d_in[2];
    const float* b_proj = (const float*)d_in[3];
    const float* W1     = (const float*)d_in[4];
    const float* b1     = (const float*)d_in[5];
    const float* W2     = (const float*)d_in[6];
    const float* b2     = (const float*)d_in[7];
    float* out = (float*)d_out;

    uint8_t* ws = (uint8_t*)d_ws;
    ushort_t* Wb   = (ushort_t*)(ws);                     // 32 MiB
    ushort_t* f16  = (ushort_t*)(ws + 33554432);          // 2 MiB
    float*    part = (float*)(ws + 33554432 + 2097152);   // 2 MiB

    convert_kernel<<<dim3((CDIM * FDIM * FDIM) / 2048), dim3(256), 0, stream>>>(W_proj, Wb);
    convert_kernel<<<dim3((BATCH * FDIM) / 2048), dim3(256), 0, stream>>>(f_feat, f16);

    gemm_fused_kernel<<<dim3(BATCH / 128, (CDIM * FDIM) / 128), dim3(256), 0, stream>>>(
        f16, Wb, t_feat, part);

    mlp_kernel<<<dim3(BATCH / 8), dim3(256), 0, stream>>>(part, b_proj, W1, b1, W2, b2, out);
}